// Round 4
// baseline (79.379 us; speedup 1.0000x reference)
//
#include <hip/hip_runtime.h>
#include <hip/hip_bf16.h>
#include <stdint.h>

#define NB 4096
#define ND 1024

typedef __attribute__((ext_vector_type(8))) short bf16x8;
typedef __attribute__((ext_vector_type(4))) float f32x4;

typedef __attribute__((address_space(3))) unsigned int lds_u32_t;
typedef const __attribute__((address_space(1))) unsigned int glb_u32_t;

__device__ __forceinline__ void gload_lds16(const unsigned short* g, unsigned short* l) {
    // 16B per lane, LDS dest = wave-uniform base + lane*16 (linear)
    __builtin_amdgcn_global_load_lds((glb_u32_t*)g, (lds_u32_t*)l, 16, 0, 0);
}

// ---------------------------------------------------------------------------
// prep: row-normalize to bf16, pack label key.
// ---------------------------------------------------------------------------
__global__ __launch_bounds__(256) void prep_kernel(
    const float* __restrict__ emb, const int* __restrict__ labels,
    unsigned short* __restrict__ z, int* __restrict__ keys)
{
    const int row = blockIdx.x;
    const int t = threadIdx.x;
    const int lane = t & 63, wid = t >> 6;
    __shared__ float wred[4];

    const float4 e4 = ((const float4*)(emb + (size_t)row * ND))[t];
    float ss = e4.x*e4.x + e4.y*e4.y + e4.z*e4.z + e4.w*e4.w;
    #pragma unroll
    for (int o = 32; o > 0; o >>= 1) ss += __shfl_xor(ss, o);
    if (lane == 0) wred[wid] = ss;
    __syncthreads();
    ss = wred[0] + wred[1] + wred[2] + wred[3];

    const float inv = 1.0f / fmaxf(sqrtf(ss), 1e-12f);
    ushort4 pk;
    {
        union { __hip_bfloat16 h; unsigned short u; } cu;
        cu.h = __float2bfloat16(e4.x * inv); pk.x = cu.u;
        cu.h = __float2bfloat16(e4.y * inv); pk.y = cu.u;
        cu.h = __float2bfloat16(e4.z * inv); pk.z = cu.u;
        cu.h = __float2bfloat16(e4.w * inv); pk.w = cu.u;
    }
    ((ushort4*)(z + (size_t)row * ND))[t] = pk;

    if (t == 0) {
        const int* lr = labels + row * 4;
        keys[row] = ((lr[3] & 7) << 24) | ((lr[0] & 7) << 16) |
                    ((lr[1] & 7) << 8)  |  (lr[2] & 7);
    }
}

// ---------------------------------------------------------------------------
// simtile: upper-triangle 128x128 tiles of S = Z Z^T / TAU.
// BK=64, double-buffered LDS (64 KB -> 2 blocks/CU = full triangle co-resident),
// T3-minimum 2-phase: STAGE(next) before COMPUTE(cur), one barrier per K-step.
// D[jj][ii] = Z[J0+jj] . Z[I0+ii]. Emits {G,T1,T2,T3} for BOTH I-rows (side A,
// reduce over jj) and J-rows (side B, reduce over ii).
// g = exp(v - 10 - pen) makes G row-shift-free: per_row = T/c - log(G) - 10.
// ---------------------------------------------------------------------------
__global__ __launch_bounds__(256) void simtile_kernel(
    const unsigned short* __restrict__ z, const int* __restrict__ keys,
    float* __restrict__ partials)
{
    // triangle decode: p -> (bj >= bi)
    const int p = blockIdx.x;
    int r = (int)((sqrtf(8.0f * p + 1.0f) - 1.0f) * 0.5f);
    while ((r + 1) * (r + 2) / 2 <= p) ++r;
    while (r * (r + 1) / 2 > p) --r;
    const int bi = p - r * (r + 1) / 2;   // I tile (columns of D)
    const int bj = r;                     // J tile (rows of D)
    const int I0 = bi * 128, J0 = bj * 128;
    const bool offdiag = (bi != bj);

    const int tid = threadIdx.x;
    const int lane = tid & 63, w = tid >> 6;
    const int lhi = lane >> 4, llo = lane & 15;
    const int wjj = w >> 1, wii = w & 1;

    __shared__ __align__(16) unsigned short ZI[2][128][64];   // 32 KB
    __shared__ __align__(16) unsigned short ZJ[2][128][64];   // 32 KB
    __shared__ int keyIs[128];
    __shared__ int keyJs[128];

    if (tid < 128) {
        keyIs[tid] = keys[I0 + tid];
        keyJs[tid] = keys[J0 + tid];
    }

    // staging: wave w covers tile rows [w*32, w*32+32).
    // per tile, 4 issues of 1KB: issue q -> rows w*32+q*8+(lane>>3), col (lane&7)*8
    const unsigned short* gI = z + (size_t)(I0 + w * 32 + (lane >> 3)) * ND + (lane & 7) * 8;
    const unsigned short* gJ = z + (size_t)(J0 + w * 32 + (lane >> 3)) * ND + (lane & 7) * 8;

    f32x4 acc[4][4];
    #pragma unroll
    for (int m = 0; m < 4; ++m)
        #pragma unroll
        for (int n = 0; n < 4; ++n)
            acc[m][n] = (f32x4){0.f, 0.f, 0.f, 0.f};

    #define STAGE(sel, ko)                                                     \
        do {                                                                   \
            _Pragma("unroll")                                                  \
            for (int q = 0; q < 4; ++q) {                                      \
                gload_lds16(gI + (size_t)q * 8 * ND + (ko), &ZI[sel][w * 32 + q * 8][0]); \
                gload_lds16(gJ + (size_t)q * 8 * ND + (ko), &ZJ[sel][w * 32 + q * 8][0]); \
            }                                                                  \
        } while (0)

    #define COMPUTE(sel)                                                       \
        do {                                                                   \
            _Pragma("unroll")                                                  \
            for (int kk = 0; kk < 2; ++kk) {                                   \
                bf16x8 a[4], b[4];                                             \
                _Pragma("unroll")                                              \
                for (int m = 0; m < 4; ++m)                                    \
                    a[m] = *(const bf16x8*)&ZJ[sel][wjj * 64 + m * 16 + llo][kk * 32 + lhi * 8]; \
                _Pragma("unroll")                                              \
                for (int n = 0; n < 4; ++n)                                    \
                    b[n] = *(const bf16x8*)&ZI[sel][wii * 64 + n * 16 + llo][kk * 32 + lhi * 8]; \
                _Pragma("unroll")                                              \
                for (int m = 0; m < 4; ++m)                                    \
                    _Pragma("unroll")                                          \
                    for (int n = 0; n < 4; ++n)                                \
                        acc[m][n] = __builtin_amdgcn_mfma_f32_16x16x32_bf16(a[m], b[n], acc[m][n], 0, 0, 0); \
            }                                                                  \
        } while (0)

    STAGE(0, 0);
    __syncthreads();                        // prologue staged
    #pragma unroll 1
    for (int t2 = 0; t2 < 8; ++t2) {
        STAGE(1, (2 * t2 + 1) * 64);        // prefetch next K-step (issue-early)
        COMPUTE(0);
        __syncthreads();                    // drain vmcnt+lgkm, barrier
        if (t2 < 7) STAGE(0, (2 * t2 + 2) * 64);
        COMPUTE(1);
        __syncthreads();
    }
    #undef STAGE
    #undef COMPUTE

    // -------- epilogue (LDS reusable now) ---------------------------------
    float (*epiA)[128][4] = (float (*)[128][4])(&ZI[0][0][0]);   // 4 KB
    float (*epiB)[128][4] = (float (*)[128][4])(&ZJ[0][0][0]);   // 4 KB

    float stA[4][4];
    #pragma unroll
    for (int n = 0; n < 4; ++n)
        #pragma unroll
        for (int s = 0; s < 4; ++s) stA[n][s] = 0.0f;

    int kI[4], iiG[4];
    #pragma unroll
    for (int n = 0; n < 4; ++n) {
        const int ii = wii * 64 + n * 16 + llo;
        kI[n]  = keyIs[ii];
        iiG[n] = I0 + ii;
    }

    #pragma unroll
    for (int m = 0; m < 4; ++m) {
        float stB[4][4];
        #pragma unroll
        for (int rr = 0; rr < 4; ++rr)
            #pragma unroll
            for (int s = 0; s < 4; ++s) stB[rr][s] = 0.0f;

        const int jjbase = wjj * 64 + m * 16 + lhi * 4;
        #pragma unroll
        for (int rr = 0; rr < 4; ++rr) {
            const int jj = jjbase + rr;
            const int jG = J0 + jj;
            const int kj = keyJs[jj];
            #pragma unroll
            for (int n = 0; n < 4; ++n) {
                const float v = acc[m][n][rr] * 10.0f;
                const int   x = kI[n] ^ kj;
                const float pen = (x & 0xFF000000) ? 1.0f : 0.0f;
                const float g = __expf(v - 10.0f - pen);
                if (iiG[n] != jG) {          // diagonal contributes nothing
                    stA[n][0] += g; stB[rr][0] += g;
                    if ((x & 0xFFFF0000) == 0) { stA[n][1] += v; stB[rr][1] += v; }
                    if ((x & 0xFFFFFF00) == 0) { stA[n][2] += v; stB[rr][2] += v; }
                    if (x == 0)                { stA[n][3] += v; stB[rr][3] += v; }
                }
            }
        }
        // side B: reduce over the 16 llo lanes (ii within this wave's half)
        #pragma unroll
        for (int rr = 0; rr < 4; ++rr)
            #pragma unroll
            for (int s = 0; s < 4; ++s) {
                float vv = stB[rr][s];
                vv += __shfl_xor(vv, 1);
                vv += __shfl_xor(vv, 2);
                vv += __shfl_xor(vv, 4);
                vv += __shfl_xor(vv, 8);
                stB[rr][s] = vv;
            }
        if (llo == 0) {
            #pragma unroll
            for (int rr = 0; rr < 4; ++rr) {
                float4 o; o.x = stB[rr][0]; o.y = stB[rr][1]; o.z = stB[rr][2]; o.w = stB[rr][3];
                *(float4*)&epiB[wii][jjbase + rr][0] = o;
            }
        }
    }

    // side A: combine the 4 lhi groups (different jj slots of same ii)
    #pragma unroll
    for (int n = 0; n < 4; ++n)
        #pragma unroll
        for (int s = 0; s < 4; ++s) {
            float vv = stA[n][s];
            vv += __shfl_xor(vv, 16);
            vv += __shfl_xor(vv, 32);
            stA[n][s] = vv;
        }
    if (lhi == 0) {
        #pragma unroll
        for (int n = 0; n < 4; ++n) {
            const int ii = wii * 64 + n * 16 + llo;
            float4 o; o.x = stA[n][0]; o.y = stA[n][1]; o.z = stA[n][2]; o.w = stA[n][3];
            *(float4*)&epiA[wjj][ii][0] = o;
        }
    }
    __syncthreads();

    if (tid < 128) {
        const float4 a0 = *(const float4*)&epiA[0][tid][0];
        const float4 a1 = *(const float4*)&epiA[1][tid][0];
        float4 o; o.x = a0.x + a1.x; o.y = a0.y + a1.y; o.z = a0.z + a1.z; o.w = a0.w + a1.w;
        *(float4*)(partials + ((size_t)bj * NB + I0 + tid) * 4) = o;
        if (offdiag) {
            const float4 b0 = *(const float4*)&epiB[0][tid][0];
            const float4 b1 = *(const float4*)&epiB[1][tid][0];
            float4 q; q.x = b0.x + b1.x; q.y = b0.y + b1.y; q.z = b0.z + b1.z; q.w = b0.w + b1.w;
            *(float4*)(partials + ((size_t)bi * NB + J0 + tid) * 4) = q;
        }
    }
}

// ---------------------------------------------------------------------------
// row reduce: block-local LDS histogram of keys (counts), then sum {G,T1,T2,T3}
// over 32 coltiles, per-level per-row values, block-reduce to 6 sums.
// ---------------------------------------------------------------------------
__global__ __launch_bounds__(256) void rowreduce_kernel(
    const float* __restrict__ partials, const int* __restrict__ keys,
    float* __restrict__ blocksums)
{
    const int tid = threadIdx.x;
    const int row = blockIdx.x * 256 + tid;
    const int lane = tid & 63, wid = tid >> 6;

    __shared__ int h3[4096];
    __shared__ int h2[512];
    __shared__ int h1[64];

    for (int i = tid; i < 4096; i += 256) h3[i] = 0;
    __syncthreads();
    for (int i = tid; i < 4096; i += 256) {
        const int k = keys[i];
        const int i3 = (((((k >> 24) & 7) * 8 + ((k >> 16) & 7)) * 8 + ((k >> 8) & 7)) * 8) + (k & 7);
        atomicAdd(&h3[i3], 1);
    }
    __syncthreads();
    for (int i = tid; i < 512; i += 256) {
        int s = 0;
        #pragma unroll
        for (int j = 0; j < 8; ++j) s += h3[i * 8 + j];
        h2[i] = s;
    }
    __syncthreads();
    if (tid < 64) {
        int s = 0;
        #pragma unroll
        for (int j = 0; j < 8; ++j) s += h2[tid * 8 + j];
        h1[tid] = s;
    }
    __syncthreads();

    float G = 0.f, T1 = 0.f, T2 = 0.f, T3 = 0.f;
    for (int ct = 0; ct < 32; ++ct) {
        const float4 u = *(const float4*)(partials + ((size_t)ct * NB + row) * 4);
        G += u.x; T1 += u.y; T2 += u.z; T3 += u.w;
    }
    const float lg = logf(fmaxf(G, 1e-30f)) + 10.0f;   // = logZ + m_i (m_i cancels)

    const int key = keys[row];
    const int i1 = ((key >> 24) & 7) * 8 + ((key >> 16) & 7);
    const int i2 = i1 * 8 + ((key >> 8) & 7);
    const int i3 = i2 * 8 + (key & 7);
    const int C[3] = {h1[i1] - 1, h2[i2] - 1, h3[i3] - 1};
    const float T[3] = {T1, T2, T3};

    float vals[6];
    #pragma unroll
    for (int l = 0; l < 3; ++l) {
        const bool valid = C[l] > 0;
        const float pr = T[l] / fmaxf((float)C[l], 1.0f) - lg;
        vals[2 * l]     = valid ? pr : 0.0f;
        vals[2 * l + 1] = valid ? 1.0f : 0.0f;
    }

    __shared__ float red[4][6];
    #pragma unroll
    for (int s = 0; s < 6; ++s) {
        float v = vals[s];
        #pragma unroll
        for (int o = 32; o > 0; o >>= 1) v += __shfl_xor(v, o);
        vals[s] = v;
    }
    if (lane == 0)
        #pragma unroll
        for (int s = 0; s < 6; ++s) red[wid][s] = vals[s];
    __syncthreads();
    if (tid == 0) {
        #pragma unroll
        for (int s = 0; s < 6; ++s)
            blocksums[blockIdx.x * 8 + s] = red[0][s] + red[1][s] + red[2][s] + red[3][s];
    }
}

// ---------------------------------------------------------------------------
// final: sum 16 block results, run the 3-level scalar loop
// ---------------------------------------------------------------------------
__global__ void final_kernel(const float* __restrict__ blocksums, float* __restrict__ out)
{
    if (threadIdx.x != 0) return;
    float sums[6] = {0, 0, 0, 0, 0, 0};
    for (int b = 0; b < 16; ++b)
        for (int s = 0; s < 6; ++s) sums[s] += blocksums[b * 8 + s];

    const float pen[3] = {2.0f, 1.41421356237309515f, 1.25992104989487319f};
    float total = 0.0f, max_lower = -INFINITY;
    int seen = 0;
    for (int l = 0; l < 3; ++l) {
        const float nv   = sums[2 * l + 1];
        const bool  any  = nv > 0.0f;
        const float mean = sums[2 * l] / fmaxf(nv, 1.0f);
        const float raw  = -mean;                    // TAU/TAU_BASE == 1
        const float lvl  = fmaxf(max_lower, raw);
        if (any) {
            total += lvl * pen[l];
            max_lower = fmaxf(max_lower, lvl);
            seen++;
        }
    }
    out[0] = total / (float)(seen > 0 ? seen : 1);
}

// ---------------------------------------------------------------------------
extern "C" void kernel_launch(void* const* d_in, const int* in_sizes, int n_in,
                              void* d_out, int out_size, void* d_ws, size_t ws_size,
                              hipStream_t stream)
{
    const float* emb    = (const float*)d_in[0];
    const int*   labels = (const int*)d_in[1];
    float*       out    = (float*)d_out;
    char*        ws     = (char*)d_ws;

    // ws layout
    unsigned short* z     = (unsigned short*)(ws);              // 8388608 B
    int*   keys     = (int*)(ws + 8388608);                     // 16384 B
    float* partials = (float*)(ws + 8404992);                   // 2097152 B
    float* bsums    = (float*)(ws + 10502144);                  // 512 B

    prep_kernel<<<NB, 256, 0, stream>>>(emb, labels, z, keys);
    simtile_kernel<<<528, 256, 0, stream>>>(z, keys, partials);
    rowreduce_kernel<<<NB / 256, 256, 0, stream>>>(partials, keys, bsums);
    final_kernel<<<1, 64, 0, stream>>>(bsums, out);
}

// Round 5
// 68.831 us; speedup vs baseline: 1.1532x; 1.1532x over previous
//
#include <hip/hip_runtime.h>
#include <hip/hip_bf16.h>
#include <stdint.h>

#define NB 4096
#define ND 1024

typedef __attribute__((ext_vector_type(8))) short bf16x8;
typedef __attribute__((ext_vector_type(4))) float f32x4;

typedef __attribute__((address_space(3))) unsigned int lds_u32_t;
typedef const __attribute__((address_space(1))) unsigned int glb_u32_t;

__device__ __forceinline__ void gload_lds16(const unsigned short* g, void* l) {
    // 16B per lane; LDS dest = wave-uniform base + lane*16 (linear)
    __builtin_amdgcn_global_load_lds((glb_u32_t*)g, (lds_u32_t*)l, 16, 0, 0);
}

// ---------------------------------------------------------------------------
// prep: row-normalize to bf16 (wave per row, no block barriers), pack label key
// ---------------------------------------------------------------------------
__global__ __launch_bounds__(256) void prep_kernel(
    const float* __restrict__ emb, const int* __restrict__ labels,
    unsigned short* __restrict__ z, int* __restrict__ keys)
{
    const int wid = threadIdx.x >> 6, lane = threadIdx.x & 63;
    const int row = blockIdx.x * 4 + wid;
    const float4* src = (const float4*)(emb + (size_t)row * ND);
    float4 v[4];
    float ss = 0.0f;
    #pragma unroll
    for (int j = 0; j < 4; ++j) {
        v[j] = src[j * 64 + lane];
        ss += v[j].x * v[j].x + v[j].y * v[j].y + v[j].z * v[j].z + v[j].w * v[j].w;
    }
    #pragma unroll
    for (int o = 1; o < 64; o <<= 1) ss += __shfl_xor(ss, o);
    const float inv = 1.0f / fmaxf(sqrtf(ss), 1e-12f);

    ushort4* dst = (ushort4*)(z + (size_t)row * ND);
    #pragma unroll
    for (int j = 0; j < 4; ++j) {
        union { __hip_bfloat16 h; unsigned short u; } cu;
        ushort4 pk;
        cu.h = __float2bfloat16(v[j].x * inv); pk.x = cu.u;
        cu.h = __float2bfloat16(v[j].y * inv); pk.y = cu.u;
        cu.h = __float2bfloat16(v[j].z * inv); pk.z = cu.u;
        cu.h = __float2bfloat16(v[j].w * inv); pk.w = cu.u;
        dst[j * 64 + lane] = pk;
    }
    if (lane == 0) {
        const int* lr = labels + row * 4;
        keys[row] = ((lr[3] & 7) << 24) | ((lr[0] & 7) << 16) |
                    ((lr[1] & 7) << 8)  |  (lr[2] & 7);
    }
}

// ---------------------------------------------------------------------------
// simtile: dense 256x256 tiles of S = Z Z^T / TAU. 8 waves (2Mx4N), BK=64.
// 4 phases per K-tile, one 16KB half-tile (A/B x kk) staged per phase via
// global_load_lds with pre-swizzled source; counted vmcnt(4) gates at phase
// 2/4 ends (never 0 in main loop); raw s_barrier; setprio around MFMA.
// LDS per-kk half layout: [256 rows][64B], physical chunk = logical ^ ((row>>1)&3)
// -> ds_read_b128 frag reads are bank-conflict-free (each 8-lane batch covers
// all 8 bank-quads). Epilogue: per-row {G,T1,T2,T3} over this block's 256 cols.
// g = exp(v-10-pen) is row-shift-free: per_row = T/c - log(G) - 10.
// ---------------------------------------------------------------------------
__global__ __launch_bounds__(512, 2) void simtile_kernel(
    const unsigned short* __restrict__ z, const int* __restrict__ keys,
    float* __restrict__ partials)
{
    const int ti = blockIdx.x >> 4;       // A panel -> output rows
    const int tj = blockIdx.x & 15;       // B panel -> output cols
    const int R0 = ti * 256, C0 = tj * 256;
    const bool diag = (ti == tj);

    const int tid = threadIdx.x;
    const int lane = tid & 63, w = tid >> 6;          // 8 waves
    const int llo = lane & 15, lhi = lane >> 4;
    const int wm = w >> 2, wn = w & 3;                // 2 x 4 wave grid

    __shared__ __align__(16) unsigned char lds[131072];  // A:2buf x 2kk x 16KB, B same at +64KB
    __shared__ int keyR[256];
    __shared__ int keyC[256];

    if (tid < 256) {
        keyR[tid] = keys[R0 + tid];
        keyC[tid] = keys[C0 + tid];
    }

    // staging source: issue idx = 2w+q covers tile rows idx*16..+16, one 64B row-slice each
    // per lane: row = idx*16 + (lane>>2), src chunk16 = (lane&3) ^ ((lane>>3)&3)  (pre-swizzle)
    const int srow0 = 2 * w * 16 + (lane >> 2);
    const int scol  = (((lane & 3) ^ ((lane >> 3) & 3)) << 3);   // bf16 elems
    const unsigned short* gA = z + (size_t)(R0 + srow0) * ND + scol;
    const unsigned short* gB = z + (size_t)(C0 + srow0) * ND + scol;
    const int sdst0 = (2 * w) * 1024;                 // byte offset of issue q=0 in half

    // read-side swizzled chunk byte offset within a 64B row
    const int rchunk = ((lhi ^ ((llo >> 1) & 3)) << 4);

    #define ABASE(buf, kk) (((buf) * 2 + (kk)) * 16384)
    #define BBASE(buf, kk) (65536 + ((buf) * 2 + (kk)) * 16384)

    #define STAGE(matSel, bufSel, kkSel, kt)                                        \
        do {                                                                        \
            const unsigned short* gsrc = (matSel) ? gB : gA;                        \
            unsigned char* dstp = lds +                                             \
                ((matSel) ? BBASE(bufSel, kkSel) : ABASE(bufSel, kkSel)) + sdst0;   \
            gload_lds16(gsrc + (size_t)(kt) * 64 + (kkSel) * 32, dstp);             \
            gload_lds16(gsrc + (size_t)16 * ND + (size_t)(kt) * 64 + (kkSel) * 32,  \
                        dstp + 1024);                                               \
        } while (0)

    f32x4 acc[8][4];
    #pragma unroll
    for (int m = 0; m < 8; ++m)
        #pragma unroll
        for (int n = 0; n < 4; ++n)
            acc[m][n] = (f32x4){0.f, 0.f, 0.f, 0.f};

    // prologue: stage all 4 halves of K-tile 0 into buf0; full drain
    STAGE(0, 0, 0, 0); STAGE(1, 0, 0, 0); STAGE(0, 0, 1, 0); STAGE(1, 0, 1, 0);
    __syncthreads();

    #pragma unroll 1
    for (int t = 0; t < 15; ++t) {
        const int buf = t & 1, nbuf = buf ^ 1;
        #pragma unroll
        for (int kk = 0; kk < 2; ++kk) {
            bf16x8 b[4];
            #pragma unroll
            for (int n = 0; n < 4; ++n)
                b[n] = *(const bf16x8*)(lds + BBASE(buf, kk) +
                                        (wn * 64 + n * 16 + llo) * 64 + rchunk);
            #pragma unroll
            for (int mh = 0; mh < 2; ++mh) {
                bf16x8 a[4];
                #pragma unroll
                for (int m = 0; m < 4; ++m)
                    a[m] = *(const bf16x8*)(lds + ABASE(buf, kk) +
                                            (wm * 128 + (mh * 4 + m) * 16 + llo) * 64 + rchunk);
                // phase p = 2*kk+mh stages half p of K-tile t+1
                if (kk == 0) { if (mh == 0) STAGE(0, nbuf, 0, t + 1); else STAGE(1, nbuf, 0, t + 1); }
                else         { if (mh == 0) STAGE(0, nbuf, 1, t + 1); else STAGE(1, nbuf, 1, t + 1); }
                __builtin_amdgcn_s_setprio(1);
                #pragma unroll
                for (int m = 0; m < 4; ++m)
                    #pragma unroll
                    for (int n = 0; n < 4; ++n)
                        acc[mh * 4 + m][n] = __builtin_amdgcn_mfma_f32_16x16x32_bf16(
                            a[m], b[n], acc[mh * 4 + m][n], 0, 0, 0);
                __builtin_amdgcn_s_setprio(0);
                if (mh == 1) asm volatile("s_waitcnt vmcnt(4)" ::: "memory");
                __builtin_amdgcn_s_barrier();
            }
        }
    }
    // peeled K-tile t=15 (buf1, no staging); vmcnt(0) before kk=1 reads
    #pragma unroll
    for (int kk = 0; kk < 2; ++kk) {
        bf16x8 b[4];
        #pragma unroll
        for (int n = 0; n < 4; ++n)
            b[n] = *(const bf16x8*)(lds + BBASE(1, kk) +
                                    (wn * 64 + n * 16 + llo) * 64 + rchunk);
        #pragma unroll
        for (int mh = 0; mh < 2; ++mh) {
            bf16x8 a[4];
            #pragma unroll
            for (int m = 0; m < 4; ++m)
                a[m] = *(const bf16x8*)(lds + ABASE(1, kk) +
                                        (wm * 128 + (mh * 4 + m) * 16 + llo) * 64 + rchunk);
            __builtin_amdgcn_s_setprio(1);
            #pragma unroll
            for (int m = 0; m < 4; ++m)
                #pragma unroll
                for (int n = 0; n < 4; ++n)
                    acc[mh * 4 + m][n] = __builtin_amdgcn_mfma_f32_16x16x32_bf16(
                        a[m], b[n], acc[mh * 4 + m][n], 0, 0, 0);
            __builtin_amdgcn_s_setprio(0);
            if (kk == 0 && mh == 1) asm volatile("s_waitcnt vmcnt(0)" ::: "memory");
            __builtin_amdgcn_s_barrier();
        }
    }
    #undef STAGE
    #undef ABASE
    #undef BBASE

    // -------- epilogue: stats per output row over this block's 256 cols -----
    float (*epi)[256][4] = (float (*)[256][4])lds;   // [wn][row][4] = 16KB

    int kC[4], tcol[4];
    #pragma unroll
    for (int n = 0; n < 4; ++n) {
        tcol[n] = wn * 64 + n * 16 + llo;
        kC[n] = keyC[tcol[n]];
    }

    #pragma unroll
    for (int mp = 0; mp < 8; ++mp) {
        float st[4][4];
        #pragma unroll
        for (int rr = 0; rr < 4; ++rr)
            #pragma unroll
            for (int s = 0; s < 4; ++s) st[rr][s] = 0.0f;

        int kR[4], trow[4];
        #pragma unroll
        for (int rr = 0; rr < 4; ++rr) {
            trow[rr] = wm * 128 + mp * 16 + lhi * 4 + rr;
            kR[rr] = keyR[trow[rr]];
        }
        #pragma unroll
        for (int n = 0; n < 4; ++n) {
            #pragma unroll
            for (int rr = 0; rr < 4; ++rr) {
                const float v = acc[mp][n][rr] * 10.0f;
                const int x = kR[rr] ^ kC[n];
                const float pen = (x & 0xFF000000) ? 1.0f : 0.0f;
                const float g = __expf(v - 10.0f - pen);
                if (!(diag && trow[rr] == tcol[n])) {
                    st[rr][0] += g;
                    if ((x & 0xFFFF0000) == 0) st[rr][1] += v;
                    if ((x & 0xFFFFFF00) == 0) st[rr][2] += v;
                    if (x == 0)                st[rr][3] += v;
                }
            }
        }
        #pragma unroll
        for (int rr = 0; rr < 4; ++rr)
            #pragma unroll
            for (int s = 0; s < 4; ++s) {
                float vv = st[rr][s];
                vv += __shfl_xor(vv, 1);
                vv += __shfl_xor(vv, 2);
                vv += __shfl_xor(vv, 4);
                vv += __shfl_xor(vv, 8);
                st[rr][s] = vv;
            }
        if (llo == 0) {
            #pragma unroll
            for (int rr = 0; rr < 4; ++rr) {
                float4 o; o.x = st[rr][0]; o.y = st[rr][1]; o.z = st[rr][2]; o.w = st[rr][3];
                *(float4*)&epi[wn][trow[rr]][0] = o;
            }
        }
    }
    __syncthreads();

    if (tid < 256) {
        const float4 s0 = *(const float4*)&epi[0][tid][0];
        const float4 s1 = *(const float4*)&epi[1][tid][0];
        const float4 s2 = *(const float4*)&epi[2][tid][0];
        const float4 s3 = *(const float4*)&epi[3][tid][0];
        float4 o;
        o.x = s0.x + s1.x + s2.x + s3.x;
        o.y = s0.y + s1.y + s2.y + s3.y;
        o.z = s0.z + s1.z + s2.z + s3.z;
        o.w = s0.w + s1.w + s2.w + s3.w;
        *(float4*)(partials + ((size_t)tj * NB + R0 + tid) * 4) = o;
    }
}

// ---------------------------------------------------------------------------
// row reduce: block-local LDS histogram of keys (counts), then sum {G,T1,T2,T3}
// over 16 coltiles, per-level per-row values, block-reduce to 6 sums.
// ---------------------------------------------------------------------------
__global__ __launch_bounds__(256) void rowreduce_kernel(
    const float* __restrict__ partials, const int* __restrict__ keys,
    float* __restrict__ blocksums)
{
    const int tid = threadIdx.x;
    const int row = blockIdx.x * 256 + tid;
    const int lane = tid & 63, wid = tid >> 6;

    __shared__ int h3[4096];
    __shared__ int h2[512];
    __shared__ int h1[64];

    for (int i = tid; i < 4096; i += 256) h3[i] = 0;
    __syncthreads();
    for (int i = tid; i < 4096; i += 256) {
        const int k = keys[i];
        const int i3 = (((((k >> 24) & 7) * 8 + ((k >> 16) & 7)) * 8 + ((k >> 8) & 7)) * 8) + (k & 7);
        atomicAdd(&h3[i3], 1);
    }
    __syncthreads();
    for (int i = tid; i < 512; i += 256) {
        int s = 0;
        #pragma unroll
        for (int j = 0; j < 8; ++j) s += h3[i * 8 + j];
        h2[i] = s;
    }
    __syncthreads();
    if (tid < 64) {
        int s = 0;
        #pragma unroll
        for (int j = 0; j < 8; ++j) s += h2[tid * 8 + j];
        h1[tid] = s;
    }
    __syncthreads();

    float G = 0.f, T1 = 0.f, T2 = 0.f, T3 = 0.f;
    for (int ct = 0; ct < 16; ++ct) {
        const float4 u = *(const float4*)(partials + ((size_t)ct * NB + row) * 4);
        G += u.x; T1 += u.y; T2 += u.z; T3 += u.w;
    }
    const float lg = logf(fmaxf(G, 1e-30f)) + 10.0f;   // = logZ + m_i (m_i cancels)

    const int key = keys[row];
    const int i1 = ((key >> 24) & 7) * 8 + ((key >> 16) & 7);
    const int i2 = i1 * 8 + ((key >> 8) & 7);
    const int i3 = i2 * 8 + (key & 7);
    const int C[3] = {h1[i1] - 1, h2[i2] - 1, h3[i3] - 1};
    const float T[3] = {T1, T2, T3};

    float vals[6];
    #pragma unroll
    for (int l = 0; l < 3; ++l) {
        const bool valid = C[l] > 0;
        const float pr = T[l] / fmaxf((float)C[l], 1.0f) - lg;
        vals[2 * l]     = valid ? pr : 0.0f;
        vals[2 * l + 1] = valid ? 1.0f : 0.0f;
    }

    __shared__ float red[4][6];
    #pragma unroll
    for (int s = 0; s < 6; ++s) {
        float v = vals[s];
        #pragma unroll
        for (int o = 32; o > 0; o >>= 1) v += __shfl_xor(v, o);
        vals[s] = v;
    }
    if (lane == 0)
        #pragma unroll
        for (int s = 0; s < 6; ++s) red[wid][s] = vals[s];
    __syncthreads();
    if (tid == 0) {
        #pragma unroll
        for (int s = 0; s < 6; ++s)
            blocksums[blockIdx.x * 8 + s] = red[0][s] + red[1][s] + red[2][s] + red[3][s];
    }
}

// ---------------------------------------------------------------------------
// final: sum 16 block results, run the 3-level scalar loop
// ---------------------------------------------------------------------------
__global__ void final_kernel(const float* __restrict__ blocksums, float* __restrict__ out)
{
    if (threadIdx.x != 0) return;
    float sums[6] = {0, 0, 0, 0, 0, 0};
    for (int b = 0; b < 16; ++b)
        for (int s = 0; s < 6; ++s) sums[s] += blocksums[b * 8 + s];

    const float pen[3] = {2.0f, 1.41421356237309515f, 1.25992104989487319f};
    float total = 0.0f, max_lower = -INFINITY;
    int seen = 0;
    for (int l = 0; l < 3; ++l) {
        const float nv   = sums[2 * l + 1];
        const bool  any  = nv > 0.0f;
        const float mean = sums[2 * l] / fmaxf(nv, 1.0f);
        const float raw  = -mean;                    // TAU/TAU_BASE == 1
        const float lvl  = fmaxf(max_lower, raw);
        if (any) {
            total += lvl * pen[l];
            max_lower = fmaxf(max_lower, lvl);
            seen++;
        }
    }
    out[0] = total / (float)(seen > 0 ? seen : 1);
}

// ---------------------------------------------------------------------------
extern "C" void kernel_launch(void* const* d_in, const int* in_sizes, int n_in,
                              void* d_out, int out_size, void* d_ws, size_t ws_size,
                              hipStream_t stream)
{
    const float* emb    = (const float*)d_in[0];
    const int*   labels = (const int*)d_in[1];
    float*       out    = (float*)d_out;
    char*        ws     = (char*)d_ws;

    // ws layout
    unsigned short* z     = (unsigned short*)(ws);              // 8388608 B
    int*   keys     = (int*)(ws + 8388608);                     // 16384 B
    float* partials = (float*)(ws + 8404992);                   // 1048576 B
    float* bsums    = (float*)(ws + 9453568);                   // 512 B

    prep_kernel<<<NB / 4, 256, 0, stream>>>(emb, labels, z, keys);
    simtile_kernel<<<256, 512, 0, stream>>>(z, keys, partials);
    rowreduce_kernel<<<NB / 256, 256, 0, stream>>>(partials, keys, bsums);
    final_kernel<<<1, 64, 0, stream>>>(bsums, out);
}